// Round 1
// baseline (484.221 us; speedup 1.0000x reference)
//
#include <hip/hip_runtime.h>
#include <math.h>

#define NROWS 4096
#define NCOLS 16384
#define NGRP  512                   // NCOLS / 32
#define TOTAL_ELEMS (67108864ULL)   // NROWS * NCOLS
#define TOTAL4      (16777216ULL)   // TOTAL_ELEMS / 4

typedef float nfloat4 __attribute__((ext_vector_type(4)));  // native vec for nt-store

// Key invariant exploited throughout: grid strides are multiples of 4096
// float4s (= one row of 16384 floats), so each thread's group index
// g = ((4*i) % 16384) / 32 = (i & 4095) >> 3 is LOOP-INVARIANT.

__global__ void init_kernel(unsigned int* __restrict__ gmax) {
    gmax[threadIdx.x] = 0u;   // 512 threads, 1 block
}

// Pass 1: per-group max(|w|). Each thread accumulates a private max over all
// its (same-group) iterations — no per-iter shuffles/atomics. Then one
// 8-lane shfl-xor cluster reduce, one LDS atomic per cluster, and a
// per-block flush (only ~32 distinct groups per block are nonzero).
__global__ void __launch_bounds__(256)
maxabs_kernel(const float4* __restrict__ w,
              unsigned int* __restrict__ gmax) {
    __shared__ unsigned int smax[NGRP];
    for (int i = threadIdx.x; i < NGRP; i += blockDim.x) smax[i] = 0u;
    __syncthreads();

    const size_t tid0   = (size_t)blockIdx.x * blockDim.x + threadIdx.x;
    const size_t stride = (size_t)gridDim.x * blockDim.x;   // ≡ 0 mod 4096
    const int g = (int)((tid0 & 4095) >> 3);                // loop-invariant

    // 2× unroll, independent accumulators: 2 outstanding float4 loads/iter.
    float m0 = 0.f, m1 = 0.f;
    size_t i = tid0;
    for (; i + stride < TOTAL4; i += 2 * stride) {
        float4 a = w[i];
        float4 b = w[i + stride];
        m0 = fmaxf(m0, fmaxf(fmaxf(fabsf(a.x), fabsf(a.y)),
                             fmaxf(fabsf(a.z), fabsf(a.w))));
        m1 = fmaxf(m1, fmaxf(fmaxf(fabsf(b.x), fabsf(b.y)),
                             fmaxf(fabsf(b.z), fabsf(b.w))));
    }
    for (; i < TOTAL4; i += stride) {
        float4 a = w[i];
        m0 = fmaxf(m0, fmaxf(fmaxf(fabsf(a.x), fabsf(a.y)),
                             fmaxf(fabsf(a.z), fabsf(a.w))));
    }
    float m = fmaxf(m0, m1);

    // 8 consecutive lanes share g (blocks are 256-aligned in tid)
    m = fmaxf(m, __shfl_xor(m, 1, 64));
    m = fmaxf(m, __shfl_xor(m, 2, 64));
    m = fmaxf(m, __shfl_xor(m, 4, 64));
    if ((threadIdx.x & 7) == 0)
        atomicMax(&smax[g], __float_as_uint(m));

    __syncthreads();
    for (int j = threadIdx.x; j < NGRP; j += blockDim.x)
        if (smax[j]) atomicMax(&gmax[j], smax[j]);
}

// Pass 1.5: read gmax bits from the output tail, overwrite tail with the
// final eps_eff (tail[0..512)) and e_base (tail[512..1024)) outputs.
__global__ void setup_kernel(const float* __restrict__ eps_param,
                             const float* __restrict__ delta,
                             float* __restrict__ tail) {
    int g = threadIdx.x;   // exactly NGRP threads, 1 block
    float ma = __uint_as_float(((const unsigned int*)tail)[g]);
    float e = 0.f;
    if (ma > 0.f) {
        int ex;
        (void)frexpf(ma, &ex);      // ma = m * 2^ex, m in [0.5, 1)
        e = (float)(ex - 1);        // floor(log2(ma)) exactly
    }
    float eps = 0.5f * tanhf(eps_param[g]);
    float ee  = fminf(fmaxf(eps + delta[g], -0.5f), 0.5f);
    tail[g]        = ee;    // output: eps_eff
    tail[NGRP + g] = e;     // output: e_base
}

__device__ __forceinline__ float quant1(float a, float s, float inv, float ee) {
    float r  = fminf(fabsf(a) * inv, 1.f);        // clip(|w|/s,0,1) — exact mul
    float sh = fminf(fmaxf(r + ee, 0.f), 1.f);    // clip(+eps_eff, 0, 1)
    float mq = rintf(sh * 8.f) * 0.125f;          // round-half-even = np.round
    float q  = copysignf(s * mq, a);
    return (a == 0.f) ? 0.f : q;                  // jnp.sign(0) == 0
}

// Pass 2: elementwise quantization. Per-thread scalars (s, inv, ee) hoisted
// out of the loop (g loop-invariant). Nontemporal stores: out is
// write-once, never re-read — don't pollute L2/L3.
__global__ void __launch_bounds__(256)
quant_kernel(const float4* __restrict__ w,
             const float* __restrict__ tail,
             float4* __restrict__ out) {
    const size_t tid0   = (size_t)blockIdx.x * blockDim.x + threadIdx.x;
    const size_t stride = (size_t)gridDim.x * blockDim.x;   // ≡ 0 mod 4096
    const int g = (int)((tid0 & 4095) >> 3);                // loop-invariant

    const float ee = tail[g];
    const int   ei = (int)tail[NGRP + g];
    const float s   = __uint_as_float((unsigned)(ei + 127) << 23);  // 2^e
    const float inv = __uint_as_float((unsigned)(127 - ei) << 23);  // 2^-e

    // 2× unroll: issue both loads before either compute chain → 2
    // outstanding VMEM ops per thread per iteration.
    size_t i = tid0;
    for (; i + stride < TOTAL4; i += 2 * stride) {
        float4 a = w[i];
        float4 b = w[i + stride];
        nfloat4 oa, ob;
        oa.x = quant1(a.x, s, inv, ee);
        oa.y = quant1(a.y, s, inv, ee);
        oa.z = quant1(a.z, s, inv, ee);
        oa.w = quant1(a.w, s, inv, ee);
        __builtin_nontemporal_store(oa, (nfloat4*)&out[i]);
        ob.x = quant1(b.x, s, inv, ee);
        ob.y = quant1(b.y, s, inv, ee);
        ob.z = quant1(b.z, s, inv, ee);
        ob.w = quant1(b.w, s, inv, ee);
        __builtin_nontemporal_store(ob, (nfloat4*)&out[i + stride]);
    }
    for (; i < TOTAL4; i += stride) {
        float4 a = w[i];
        nfloat4 oa;
        oa.x = quant1(a.x, s, inv, ee);
        oa.y = quant1(a.y, s, inv, ee);
        oa.z = quant1(a.z, s, inv, ee);
        oa.w = quant1(a.w, s, inv, ee);
        __builtin_nontemporal_store(oa, (nfloat4*)&out[i]);
    }
}

extern "C" void kernel_launch(void* const* d_in, const int* in_sizes, int n_in,
                              void* d_out, int out_size, void* d_ws, size_t ws_size,
                              hipStream_t stream) {
    const float* weight    = (const float*)d_in[0];
    const float* eps_param = (const float*)d_in[1];
    const float* delta     = (const float*)d_in[2];
    float* out  = (float*)d_out;
    float* tail = out + TOTAL_ELEMS;   // 1024 floats: gmax scratch -> outputs

    init_kernel<<<1, NGRP, 0, stream>>>((unsigned int*)tail);
    maxabs_kernel<<<2048, 256, 0, stream>>>((const float4*)weight,
                                            (unsigned int*)tail);
    setup_kernel<<<1, NGRP, 0, stream>>>(eps_param, delta, tail);
    quant_kernel<<<8192, 256, 0, stream>>>((const float4*)weight, tail,
                                           (float4*)out);
}

// Round 3
// 483.744 us; speedup vs baseline: 1.0010x; 1.0010x over previous
//
#include <hip/hip_runtime.h>
#include <math.h>

#define NROWS 4096
#define NCOLS 16384
#define NGRP  512                   // NCOLS / 32
#define TOTAL_ELEMS (67108864ULL)   // NROWS * NCOLS
#define TOTAL4      (16777216ULL)   // TOTAL_ELEMS / 4

typedef float nfloat4 __attribute__((ext_vector_type(4)));  // native vec for nt-store

// Key invariant exploited throughout: grid strides are multiples of 4096
// float4s (= one row of 16384 floats), so each thread's group index
// g = ((4*i) % 16384) / 32 = (i & 4095) >> 3 is LOOP-INVARIANT.

__global__ void init_kernel(unsigned int* __restrict__ gmax) {
    gmax[threadIdx.x] = 0u;   // 512 threads, 1 block (gmax lives in d_ws)
}

// Pass 1: per-group max(|w|). Private per-thread max over all (same-group)
// iterations, 8-lane shfl-xor cluster reduce, one LDS atomic per cluster,
// per-block flush of the ~32 nonzero groups.
__global__ void __launch_bounds__(256)
maxabs_kernel(const float4* __restrict__ w,
              unsigned int* __restrict__ gmax) {
    __shared__ unsigned int smax[NGRP];
    for (int i = threadIdx.x; i < NGRP; i += blockDim.x) smax[i] = 0u;
    __syncthreads();

    const size_t tid0   = (size_t)blockIdx.x * blockDim.x + threadIdx.x;
    const size_t stride = (size_t)gridDim.x * blockDim.x;   // ≡ 0 mod 4096
    const int g = (int)((tid0 & 4095) >> 3);                // loop-invariant

    float m0 = 0.f, m1 = 0.f;
    size_t i = tid0;
    for (; i + stride < TOTAL4; i += 2 * stride) {
        float4 a = w[i];
        float4 b = w[i + stride];
        m0 = fmaxf(m0, fmaxf(fmaxf(fabsf(a.x), fabsf(a.y)),
                             fmaxf(fabsf(a.z), fabsf(a.w))));
        m1 = fmaxf(m1, fmaxf(fmaxf(fabsf(b.x), fabsf(b.y)),
                             fmaxf(fabsf(b.z), fabsf(b.w))));
    }
    for (; i < TOTAL4; i += stride) {
        float4 a = w[i];
        m0 = fmaxf(m0, fmaxf(fmaxf(fabsf(a.x), fabsf(a.y)),
                             fmaxf(fabsf(a.z), fabsf(a.w))));
    }
    float m = fmaxf(m0, m1);

    // 8 consecutive lanes share g (blocks are 256-aligned in tid)
    m = fmaxf(m, __shfl_xor(m, 1, 64));
    m = fmaxf(m, __shfl_xor(m, 2, 64));
    m = fmaxf(m, __shfl_xor(m, 4, 64));
    if ((threadIdx.x & 7) == 0)
        atomicMax(&smax[g], __float_as_uint(m));

    __syncthreads();
    for (int j = threadIdx.x; j < NGRP; j += blockDim.x)
        if (smax[j]) atomicMax(&gmax[j], smax[j]);
}

__device__ __forceinline__ float quant1(float a, float s, float inv, float ee) {
    float r  = fminf(fabsf(a) * inv, 1.f);        // clip(|w|/s,0,1) — exact mul
    float sh = fminf(fmaxf(r + ee, 0.f), 1.f);    // clip(+eps_eff, 0, 1)
    float mq = rintf(sh * 8.f) * 0.125f;          // round-half-even = np.round
    float q  = copysignf(s * mq, a);
    return (a == 0.f) ? 0.f : q;                  // jnp.sign(0) == 0
}

// Pass 2 (fused setup + quant): every thread derives (ee, s, inv) for its
// loop-invariant group from gmax/eps_param/delta directly (~30 VALU once).
// 512 designated threads also write the eps_eff / e_base output tail.
// The sweep runs in REVERSE so the lines maxabs touched last (still resident
// in the 256 MiB Infinity Cache; weight is 268 MB) are re-read as L3 hits.
// Nontemporal stores keep the output stream from evicting them.
__global__ void __launch_bounds__(256)
quant_kernel(const float4* __restrict__ w,
             const float* __restrict__ eps_param,
             const float* __restrict__ delta,
             const unsigned int* __restrict__ gmax,
             float* __restrict__ tail,
             float4* __restrict__ out) {
    const size_t tid0   = (size_t)blockIdx.x * blockDim.x + threadIdx.x;
    const size_t stride = (size_t)gridDim.x * blockDim.x;   // 2,097,152 ≡ 0 mod 4096
    const int g = (int)((tid0 & 4095) >> 3);                // loop-invariant

    float ma = __uint_as_float(gmax[g]);
    float e = 0.f;
    if (ma > 0.f) {
        int ex;
        (void)frexpf(ma, &ex);      // ma = m * 2^ex, m in [0.5, 1)
        e = (float)(ex - 1);        // floor(log2(ma)) exactly
    }
    float eps = 0.5f * tanhf(eps_param[g]);
    float ee  = fminf(fmaxf(eps + delta[g], -0.5f), 0.5f);
    const int   ei  = (int)e;
    const float s   = __uint_as_float((unsigned)(ei + 127) << 23);  // 2^e
    const float inv = __uint_as_float((unsigned)(127 - ei) << 23);  // 2^-e

    // one writer per group lives in blocks 0..15
    if (tid0 < 4096 && (tid0 & 7) == 0) {
        tail[g]        = ee;    // output: eps_eff
        tail[NGRP + g] = e;     // output: e_base
    }

    // exactly 8 iterations: TOTAL4 == 8 * stride (grid fixed in launcher)
    #pragma unroll
    for (int k = 7; k >= 0; --k) {
        size_t i = tid0 + (size_t)k * stride;
        float4 v = w[i];
        nfloat4 o;
        o.x = quant1(v.x, s, inv, ee);
        o.y = quant1(v.y, s, inv, ee);
        o.z = quant1(v.z, s, inv, ee);
        o.w = quant1(v.w, s, inv, ee);
        __builtin_nontemporal_store(o, (nfloat4*)&out[i]);
    }
}

extern "C" void kernel_launch(void* const* d_in, const int* in_sizes, int n_in,
                              void* d_out, int out_size, void* d_ws, size_t ws_size,
                              hipStream_t stream) {
    const float* weight    = (const float*)d_in[0];
    const float* eps_param = (const float*)d_in[1];
    const float* delta     = (const float*)d_in[2];
    float* out  = (float*)d_out;
    float* tail = out + TOTAL_ELEMS;            // 1024 floats: eps_eff + e_base
    unsigned int* gmax = (unsigned int*)d_ws;   // 512 uints of scratch

    init_kernel<<<1, NGRP, 0, stream>>>(gmax);
    maxabs_kernel<<<2048, 256, 0, stream>>>((const float4*)weight, gmax);
    // 8192 blocks * 256 threads = 2,097,152 threads; TOTAL4 / threads = 8 iters
    quant_kernel<<<8192, 256, 0, stream>>>((const float4*)weight, eps_param,
                                           delta, gmax, tail, (float4*)out);
}